// Round 17
// baseline (112.915 us; speedup 1.0000x reference)
//
#include <hip/hip_runtime.h>
#include <hip/hip_bf16.h>
#include <cstdint>

#define B_    8
#define S_    1024
#define DIM_  768
#define H_    12
#define HD_   64
// Q is pre-scaled by SCALE*log2(e) in the Q-GEMM epilogue -> scores are in
// log2 domain; softmax uses v_exp_f32 (2^x) directly with a FIXED reference
// point C=1 (cancels in O = sum(p*v)/sum(p)). The "- 1.0f" also guarantees a
// compiler VALU op between the MFMA acc and the inline-asm v_exp_f32.
#define QL2S_ 0.1803368801111204f

typedef __attribute__((ext_vector_type(8))) __bf16 bf16x8;
typedef __attribute__((ext_vector_type(4))) float  f32x4;

// RNE float->bf16 (bit pattern as short)
__device__ __forceinline__ short f2bf(float f) {
  union { float f; uint32_t u; } a;
  a.f = f;
  uint32_t u = a.u;
  uint32_t r = (u + 0x7FFFu + ((u >> 16) & 1u)) >> 16;
  return (short)r;
}

// 2^x via v_exp_f32 (s_nop covers the trans->VALU hazard window).
// CONTRACT: output feeds only compiler-generated VALU ops, never MFMA directly.
__device__ __forceinline__ float exp2a(float x) {
  float r;
  asm("v_exp_f32 %0, %1\n\ts_nop 1" : "=v"(r) : "v"(x));
  return r;
}

// pack 2 f32 -> 2 bf16 in one u32 (RNE); result goes to LDS (ds_write), which
// is hazard-safe (unlike feeding MFMA directly - R14 lesson).
__device__ __forceinline__ uint32_t cvtpk(float a, float b) {
  uint32_t r;
  asm("v_cvt_pk_bf16_f32 %0, %1, %2" : "=v"(r) : "v"(a), "v"(b));
  return r;
}

__device__ __forceinline__ void gll16(const void* g, void* l) {
  __builtin_amdgcn_global_load_lds((const __attribute__((address_space(1))) void*)g,
                                   (__attribute__((address_space(3))) void*)l, 16, 0, 0);
}

// XOR-swizzled byte offset for [row][64] bf16 tiles (128B rows, 8x16B granules)
// PROVEN conflict-free for the b128 fragment reads (0 SQ_LDS_BANK_CONFLICT).
__device__ __forceinline__ int swz(int row, int col) {
  return row * 128 + ((((col >> 3) ^ (row & 7)) & 7) << 4) + ((col & 7) << 1);
}

// ---------------- fused prep: weight transposes (z=0..3) + x cvt (z=4) ----------------
__global__ __launch_bounds__(256) void k_prep(const float* __restrict__ x,
                                              const float* __restrict__ W0,
                                              const float* __restrict__ W1,
                                              const float* __restrict__ W2,
                                              const float* __restrict__ W3,
                                              short* __restrict__ xb,
                                              short* o0, short* o1,
                                              short* o2, short* o3) {
  const int tx = threadIdx.x, ty = threadIdx.y;
  if (blockIdx.z == 4) {
    const int tid = ty * 32 + tx;
    int i = (blockIdx.y * 24 + blockIdx.x) * 256 + tid;
    const int n4 = 8192 * 768 / 4;
    const int nthr = 24 * 24 * 256;
    for (; i < n4; i += nthr) {
      const float4 v = ((const float4*)x)[i];
      short4 o;
      o.x = f2bf(v.x); o.y = f2bf(v.y); o.z = f2bf(v.z); o.w = f2bf(v.w);
      ((short4*)xb)[i] = o;
    }
    return;
  }
  const float* in = blockIdx.z == 0 ? W0 : blockIdx.z == 1 ? W1 : blockIdx.z == 2 ? W2 : W3;
  short* out = blockIdx.z == 0 ? o0 : blockIdx.z == 1 ? o1 : blockIdx.z == 2 ? o2 : o3;
  __shared__ float tile[32][33];
  const int bx = blockIdx.x * 32, by = blockIdx.y * 32;
#pragma unroll
  for (int j = 0; j < 32; j += 8)
    tile[ty + j][tx] = in[(size_t)(by + ty + j) * DIM_ + bx + tx];
  __syncthreads();
#pragma unroll
  for (int j = 0; j < 32; j += 8)
    out[(size_t)(bx + ty + j) * DIM_ + by + tx] = f2bf(tile[tx][ty + j]);
}

// ---------------- GEMM body: C[M][N] = A[M][768] * Bt[N][768]^T + bias ----------------
// BK=32, double-buffered 32KB LDS -> 4-5 blocks/CU (was 2 at BK=64/64KB).
// Each 128x32 K-tile is PACKED into a [64 row][64 col] LDS tile (rows 64-127
// occupy cols 32-63), so the proven 128B-row swz applies unchanged:
// fragment read = swz(m*16+lo, wr*32 + hi*8), identical conflict-free pattern
// as the attn K/V tiles. Stage source carries the packed+swizzle inverse.
// Single barrier per K-step, issue-early (R8/R10 proven structure).
template <int MODE, bool QS>
__device__ __forceinline__ void gemm_body(char* smem,
                                          const short* __restrict__ A,
                                          const short* __restrict__ Bt,
                                          const float* __restrict__ bias,
                                          void* __restrict__ out,
                                          int bm, int bn) {
  char* As = smem;           // [2][8192]  A K-tiles (packed 64x64)
  char* Bs = smem + 16384;   // [2][8192]  B K-tiles (packed 64x64)
  const int tid = threadIdx.x;
  const int l = tid & 63, w = tid >> 6;
  const int hi = l >> 4, lo = l & 15;
  const int wr = w >> 1, wc = w & 1;

  // stage one packed 128x32 tile pair (8KB each = 512 slots; 2 slots/thread)
  auto stage = [&](int ks, int bo) {
#pragma unroll
    for (int i = 0; i < 2; ++i) {
      const int gl = i * 256 + tid;
      const int row64 = gl >> 3;
      const int gs = (gl & 7) ^ (row64 & 7);
      gll16(A + (size_t)(bm * 128 + (gs >> 2) * 64 + row64) * DIM_ + ks * 32 + (gs & 3) * 8,
            As + bo + gl * 16);
    }
#pragma unroll
    for (int i = 0; i < 2; ++i) {
      const int gl = i * 256 + tid;
      const int row64 = gl >> 3;
      const int gs = (gl & 7) ^ (row64 & 7);
      gll16(Bt + (size_t)(bn * 128 + (gs >> 2) * 64 + row64) * DIM_ + ks * 32 + (gs & 3) * 8,
            Bs + bo + gl * 16);
    }
  };

  f32x4 acc[4][4];
  const f32x4 zz = {0.f, 0.f, 0.f, 0.f};
#pragma unroll
  for (int m = 0; m < 4; ++m)
#pragma unroll
    for (int n = 0; n < 4; ++n) acc[m][n] = zz;

  stage(0, 0);
  __syncthreads();

  for (int ks = 0; ks < 24; ++ks) {
    const int cu = (ks & 1) << 13;  // 0 / 8192
    if (ks < 23) stage(ks + 1, cu ^ 8192);  // issue-early: lands during compute
    bf16x8 a[4], b[4];
#pragma unroll
    for (int m = 0; m < 4; ++m)
      a[m] = *(const bf16x8*)(As + cu + swz(m * 16 + lo, wr * 32 + hi * 8));
#pragma unroll
    for (int n = 0; n < 4; ++n)
      b[n] = *(const bf16x8*)(Bs + cu + swz(n * 16 + lo, wc * 32 + hi * 8));
#pragma unroll
    for (int m = 0; m < 4; ++m)
#pragma unroll
      for (int n = 0; n < 4; ++n)
        acc[m][n] = __builtin_amdgcn_mfma_f32_16x16x32_bf16(a[m], b[n], acc[m][n], 0, 0, 0);
    __syncthreads();
  }

#pragma unroll
  for (int m = 0; m < 4; ++m) {
#pragma unroll
    for (int n = 0; n < 4; ++n) {
#pragma unroll
      for (int r = 0; r < 4; ++r) {
        const int R = bm * 128 + wr * 64 + m * 16 + hi * 4 + r;
        const int C = bn * 128 + wc * 64 + n * 16 + lo;
        float v = acc[m][n][r] + bias[MODE == 1 ? R : C];
        if (QS) v *= QL2S_;
        if (MODE == 0) {
          ((short*)out)[((size_t)((R >> 10) * H_ + (C >> 6)) * S_ + (R & 1023)) * HD_ + (C & 63)] = f2bf(v);
        } else if (MODE == 1) {
          ((short*)out)[((size_t)((C >> 10) * H_ + (R >> 6)) * HD_ + (R & 63)) * S_ + (C & 1023)] = f2bf(v);
        } else {
          ((float*)out)[(size_t)R * DIM_ + C] = v;
        }
      }
    }
  }
}

// fused QKV: grid (64, 6, 3)
__global__ __launch_bounds__(256, 4) void k_gemm_qkv(const short* __restrict__ xb,
                                                     const short* __restrict__ WqT,
                                                     const short* __restrict__ WkT,
                                                     const short* __restrict__ WvT,
                                                     const float* __restrict__ bq,
                                                     const float* __restrict__ bk,
                                                     const float* __restrict__ bv,
                                                     short* qo, short* ko, short* vo) {
  __shared__ alignas(16) char smem[32768];
  if (blockIdx.z == 0)
    gemm_body<0, true>(smem, xb, WqT, bq, qo, blockIdx.x, blockIdx.y);
  else if (blockIdx.z == 1)
    gemm_body<0, false>(smem, xb, WkT, bk, ko, blockIdx.x, blockIdx.y);
  else
    gemm_body<1, false>(smem, WvT, xb, bv, vo, blockIdx.y, blockIdx.x);
}

// output projection: grid (6, 64)
__global__ __launch_bounds__(256, 4) void k_gemm_proj(const short* __restrict__ A,
                                                      const short* __restrict__ Bt,
                                                      const float* __restrict__ bias,
                                                      float* out) {
  __shared__ alignas(16) char smem[32768];
  gemm_body<2, false>(smem, A, Bt, bias, out, blockIdx.y, blockIdx.x);
}

// ---------------- flash attention (R13 config: best measured, 40.5us) ----------------
// grid: 768 blocks of 256 threads (4 waves x 32 q-rows); 3 blocks/CU, all
// co-resident. Head-local XCD mapping (qt=bid/96, bh=bid%96): K/V L2-resident
// (FETCH ~20MB measured). Swapped QK^T (mfma(A=K,B=Q)) -> lane holds
// S[q=lo][kv=nb*16+hi*4+r]; P packs via v_cvt_pk_bf16_f32 -> ds_write_b64;
// PV reads P as b128 A-frags. T5 setprio around both MFMA clusters.
__global__ __launch_bounds__(256, 3) void k_attn(const short* __restrict__ qw,
                                                 const short* __restrict__ kw,
                                                 const short* __restrict__ vtw,
                                                 short* __restrict__ ow) {
  __shared__ alignas(16) char smem[49152];
  char* Kb = smem;            // [2][8192]  K tiles (64 kv x 64 d)
  char* Vb = smem + 16384;    // [2][8192]  Vt tiles (64 d x 64 s)
  char* Ps = smem + 32768;    // [16384]    P (128 q x 64 kv), per-wave quadrants
  const int tid = threadIdx.x;
  const int l = tid & 63, w = tid >> 6;
  const int hi = l >> 4, lo = l & 15;
  const int qt = blockIdx.x / 96;   // head-local XCD: bid%8 == bh%8
  const int bh = blockIdx.x % 96;

  const short* qg = qw  + (size_t)bh * (S_ * HD_) + (qt * 128) * HD_;
  const short* kg = kw  + (size_t)bh * (S_ * HD_);
  const short* vg = vtw + (size_t)bh * (S_ * HD_);

  auto stage = [&](int T, int bufo) {
#pragma unroll
    for (int i = 0; i < 2; ++i) {
      const int gl = i * 256 + tid;
      const int row = gl >> 3;
      const int g = (gl & 7) ^ (row & 7);
      gll16(kg + (T * 64 + row) * 64 + g * 8, Kb + bufo + gl * 16);
    }
#pragma unroll
    for (int i = 0; i < 2; ++i) {
      const int gl = i * 256 + tid;
      const int row = gl >> 3;
      const int g = (gl & 7) ^ (row & 7);
      gll16(vg + row * 1024 + T * 64 + g * 8, Vb + bufo + gl * 16);
    }
  };

  bf16x8 aQ[2][2];
#pragma unroll
  for (int m = 0; m < 2; ++m)
#pragma unroll
    for (int kk = 0; kk < 2; ++kk)
      aQ[m][kk] = *(const bf16x8*)(qg + (w * 32 + m * 16 + lo) * HD_ + kk * 32 + hi * 8);

  f32x4 o_acc[2][4];
  const f32x4 zz = {0.f, 0.f, 0.f, 0.f};
#pragma unroll
  for (int m = 0; m < 2; ++m)
#pragma unroll
    for (int db = 0; db < 4; ++db) o_acc[m][db] = zz;
  float lsum[2] = {0.f, 0.f};

  stage(0, 0);
  __syncthreads();

  for (int t = 0; t < 16; ++t) {
    const int cu = (t & 1) << 13;
    if (t < 15) stage(t + 1, cu ^ 8192);  // issue-early: lands during compute

    // ---- S^T = K Q^T : lane holds S[q=lo][kv=nb*16+hi*4+r]
    f32x4 sacc[2][4];
#pragma unroll
    for (int m = 0; m < 2; ++m)
#pragma unroll
      for (int nb = 0; nb < 4; ++nb) sacc[m][nb] = zz;
    __builtin_amdgcn_s_setprio(1);
#pragma unroll
    for (int kk = 0; kk < 2; ++kk) {
#pragma unroll
      for (int nb = 0; nb < 4; ++nb) {
        const bf16x8 bK = *(const bf16x8*)(Kb + cu + swz(nb * 16 + lo, kk * 32 + hi * 8));
#pragma unroll
        for (int m = 0; m < 2; ++m)
          sacc[m][nb] = __builtin_amdgcn_mfma_f32_16x16x32_bf16(bK, aQ[m][kk], sacc[m][nb], 0, 0, 0);
      }
    }
    __builtin_amdgcn_s_setprio(0);

    // ---- p = 2^(s-1); pack pairs (RNE) and store 4 kv as one b64 ----
#pragma unroll
    for (int m = 0; m < 2; ++m) {
#pragma unroll
      for (int nb = 0; nb < 4; ++nb) {
        const float p0 = exp2a(sacc[m][nb][0] - 1.0f);
        const float p1 = exp2a(sacc[m][nb][1] - 1.0f);
        const float p2 = exp2a(sacc[m][nb][2] - 1.0f);
        const float p3 = exp2a(sacc[m][nb][3] - 1.0f);
        lsum[m] += (p0 + p1) + (p2 + p3);
        uint2 pk;
        pk.x = cvtpk(p0, p1);
        pk.y = cvtpk(p2, p3);
        *(uint2*)(Ps + swz(w * 32 + m * 16 + lo, nb * 16 + hi * 4)) = pk;
      }
    }
    asm volatile("s_waitcnt lgkmcnt(0)" ::: "memory");
    __builtin_amdgcn_sched_barrier(0);

    // ---- O += P V (P A-frags via ds_read_b128, V from LDS) ----
    __builtin_amdgcn_s_setprio(1);
#pragma unroll
    for (int kk = 0; kk < 2; ++kk) {
      bf16x8 aP[2];
#pragma unroll
      for (int m = 0; m < 2; ++m)
        aP[m] = *(const bf16x8*)(Ps + swz(w * 32 + m * 16 + lo, kk * 32 + hi * 8));
#pragma unroll
      for (int db = 0; db < 4; ++db) {
        const bf16x8 bV = *(const bf16x8*)(Vb + cu + swz(db * 16 + lo, kk * 32 + hi * 8));
#pragma unroll
        for (int m = 0; m < 2; ++m)
          o_acc[m][db] = __builtin_amdgcn_mfma_f32_16x16x32_bf16(aP[m], bV, o_acc[m][db], 0, 0, 0);
      }
    }
    __builtin_amdgcn_s_setprio(0);

    __syncthreads();
  }

  // epilogue: complete l over kv, redistribute to the o_acc row layout
  float lF[2];
#pragma unroll
  for (int m = 0; m < 2; ++m) {
    float s = lsum[m];
    s += __shfl_xor(s, 16, 64);
    s += __shfl_xor(s, 32, 64);
    lF[m] = s;  // full row sum for q = lo (all hi groups)
  }
  const int b = bh / H_, h = bh % H_;
#pragma unroll
  for (int m = 0; m < 2; ++m) {
#pragma unroll
    for (int r = 0; r < 4; ++r) {
      const float lr = __shfl(lF[m], hi * 4 + r, 64);
      const float inv = 1.0f / lr;
      const int sg = qt * 128 + w * 32 + m * 16 + hi * 4 + r;
#pragma unroll
      for (int db = 0; db < 4; ++db)
        ow[((size_t)(b * S_ + sg)) * DIM_ + h * HD_ + db * 16 + lo] = f2bf(o_acc[m][db][r] * inv);
    }
  }
}

extern "C" void kernel_launch(void* const* d_in, const int* in_sizes, int n_in,
                              void* d_out, int out_size, void* d_ws, size_t ws_size,
                              hipStream_t stream) {
  const float* x  = (const float*)d_in[0];
  const float* Wq = (const float*)d_in[1];
  const float* bq = (const float*)d_in[2];
  const float* Wk = (const float*)d_in[3];
  const float* bk = (const float*)d_in[4];
  const float* Wv = (const float*)d_in[5];
  const float* bv = (const float*)d_in[6];
  const float* Wp = (const float*)d_in[7];
  const float* bp = (const float*)d_in[8];

  char* ws = (char*)d_ws;
  size_t off = 0;
  auto alloc = [&](size_t bytes) {
    char* p = ws + off;
    off += (bytes + 255) & ~(size_t)255;
    return p;
  };
  short* xb  = (short*)alloc((size_t)8192 * 768 * 2);
  short* WqT = (short*)alloc((size_t)768 * 768 * 2);
  short* WkT = (short*)alloc((size_t)768 * 768 * 2);
  short* WvT = (short*)alloc((size_t)768 * 768 * 2);
  short* WpT = (short*)alloc((size_t)768 * 768 * 2);
  short* qwv = (short*)alloc((size_t)96 * 1024 * 64 * 2);
  short* kwv = (short*)alloc((size_t)96 * 1024 * 64 * 2);
  short* vtw = (short*)alloc((size_t)96 * 1024 * 64 * 2);
  short* owv = (short*)alloc((size_t)8192 * 768 * 2);

  dim3 tb(32, 8), tg(24, 24, 5);
  k_prep<<<tg, tb, 0, stream>>>(x, Wq, Wk, Wv, Wp, xb, WqT, WkT, WvT, WpT);

  k_gemm_qkv<<<dim3(64, 6, 3), 256, 0, stream>>>(xb, WqT, WkT, WvT, bq, bk, bv, qwv, kwv, vtw);

  k_attn<<<B_ * H_ * (S_ / 128), 256, 0, stream>>>(qwv, kwv, vtw, owv);

  k_gemm_proj<<<dim3(6, 64), 256, 0, stream>>>(owv, WpT, bp, (float*)d_out);
}

// Round 18
// 100.692 us; speedup vs baseline: 1.1214x; 1.1214x over previous
//
#include <hip/hip_runtime.h>
#include <hip/hip_bf16.h>
#include <cstdint>

#define B_    8
#define S_    1024
#define DIM_  768
#define H_    12
#define HD_   64
// Q is pre-scaled by SCALE*log2(e) in the Q-GEMM epilogue -> scores are in
// log2 domain; softmax uses v_exp_f32 (2^x) directly with a FIXED reference
// point C=1 (cancels in O = sum(p*v)/sum(p); log2-domain scores sigma~1.5-2
// -> no overflow). The "- 1.0f" also guarantees a compiler VALU op between
// the MFMA accumulator and the inline-asm v_exp_f32 (hazard shield).
#define QL2S_ 0.1803368801111204f

typedef __attribute__((ext_vector_type(8))) __bf16 bf16x8;
typedef __attribute__((ext_vector_type(4))) float  f32x4;

// RNE float->bf16 (bit pattern as short)
__device__ __forceinline__ short f2bf(float f) {
  union { float f; uint32_t u; } a;
  a.f = f;
  uint32_t u = a.u;
  uint32_t r = (u + 0x7FFFu + ((u >> 16) & 1u)) >> 16;
  return (short)r;
}

// 2^x via v_exp_f32 (s_nop covers the trans->VALU hazard window).
// CONTRACT: output feeds only compiler-generated VALU ops, never MFMA directly.
__device__ __forceinline__ float exp2a(float x) {
  float r;
  asm("v_exp_f32 %0, %1\n\ts_nop 1" : "=v"(r) : "v"(x));
  return r;
}

// pack 2 f32 -> 2 bf16 in one u32 (RNE); result goes to LDS (ds_write), which
// is hazard-safe (unlike feeding MFMA directly - R14 lesson).
__device__ __forceinline__ uint32_t cvtpk(float a, float b) {
  uint32_t r;
  asm("v_cvt_pk_bf16_f32 %0, %1, %2" : "=v"(r) : "v"(a), "v"(b));
  return r;
}

__device__ __forceinline__ void gll16(const void* g, void* l) {
  __builtin_amdgcn_global_load_lds((const __attribute__((address_space(1))) void*)g,
                                   (__attribute__((address_space(3))) void*)l, 16, 0, 0);
}

// XOR-swizzled byte offset for [row][64] bf16 tiles (128B rows, 8x16B granules)
// PROVEN conflict-free for the b128 fragment reads (0 SQ_LDS_BANK_CONFLICT).
__device__ __forceinline__ int swz(int row, int col) {
  return row * 128 + ((((col >> 3) ^ (row & 7)) & 7) << 4) + ((col & 7) << 1);
}

// ---------------- fused prep: weight transposes (z=0..3) + x cvt (z=4) ----------------
// grid (24, 24, 5), block (32, 8).
__global__ __launch_bounds__(256) void k_prep(const float* __restrict__ x,
                                              const float* __restrict__ W0,
                                              const float* __restrict__ W1,
                                              const float* __restrict__ W2,
                                              const float* __restrict__ W3,
                                              short* __restrict__ xb,
                                              short* o0, short* o1,
                                              short* o2, short* o3) {
  const int tx = threadIdx.x, ty = threadIdx.y;
  if (blockIdx.z == 4) {
    const int tid = ty * 32 + tx;
    int i = (blockIdx.y * 24 + blockIdx.x) * 256 + tid;
    const int n4 = 8192 * 768 / 4;
    const int nthr = 24 * 24 * 256;
    for (; i < n4; i += nthr) {
      const float4 v = ((const float4*)x)[i];
      short4 o;
      o.x = f2bf(v.x); o.y = f2bf(v.y); o.z = f2bf(v.z); o.w = f2bf(v.w);
      ((short4*)xb)[i] = o;
    }
    return;
  }
  const float* in = blockIdx.z == 0 ? W0 : blockIdx.z == 1 ? W1 : blockIdx.z == 2 ? W2 : W3;
  short* out = blockIdx.z == 0 ? o0 : blockIdx.z == 1 ? o1 : blockIdx.z == 2 ? o2 : o3;
  __shared__ float tile[32][33];
  const int bx = blockIdx.x * 32, by = blockIdx.y * 32;
#pragma unroll
  for (int j = 0; j < 32; j += 8)
    tile[ty + j][tx] = in[(size_t)(by + ty + j) * DIM_ + bx + tx];
  __syncthreads();
#pragma unroll
  for (int j = 0; j < 32; j += 8)
    out[(size_t)(bx + ty + j) * DIM_ + by + tx] = f2bf(tile[tx][ty + j]);
}

// ---------------- GEMM body: C[M][N] = A[M][768] * Bt[N][768]^T + bias ----------------
// BK=64, double-buffered (64KB LDS), proven 128B-row swz layout, single
// barrier per K-step: issue stage(k+1) -> compute(k) (32 MFMA) -> barrier.
// MODE 0: out bf16, split-heads [b,h,s,d]   (QS: scale by QL2S_ for Q)
// MODE 1: out bf16, V-transposed [b,h,d,s]
// MODE 2: out f32, row-major [M][N]
template <int MODE, bool QS>
__device__ __forceinline__ void gemm_body(char* smem,
                                          const short* __restrict__ A,
                                          const short* __restrict__ Bt,
                                          const float* __restrict__ bias,
                                          void* __restrict__ out,
                                          int bm, int bn) {
  char* As = smem;           // [2][128][64] bf16 (2 x 16KB)
  char* Bs = smem + 32768;   // [2][128][64] bf16
  const int tid = threadIdx.x;
  const int l = tid & 63, w = tid >> 6;
  const int hi = l >> 4, lo = l & 15;
  const int wr = w >> 1, wc = w & 1;

  auto stageA = [&](int ks, int bo) {
#pragma unroll
    for (int i = 0; i < 4; ++i) {
      const int gl = i * 256 + tid;
      const int row = gl >> 3;
      const int g = (gl & 7) ^ (row & 7);
      gll16(A + (size_t)(bm * 128 + row) * DIM_ + ks * 64 + g * 8, As + bo + gl * 16);
    }
  };
  auto stageB = [&](int ks, int bo) {
#pragma unroll
    for (int i = 0; i < 4; ++i) {
      const int gl = i * 256 + tid;
      const int row = gl >> 3;
      const int g = (gl & 7) ^ (row & 7);
      gll16(Bt + (size_t)(bn * 128 + row) * DIM_ + ks * 64 + g * 8, Bs + bo + gl * 16);
    }
  };

  f32x4 acc[4][4];
  const f32x4 zz = {0.f, 0.f, 0.f, 0.f};
#pragma unroll
  for (int m = 0; m < 4; ++m)
#pragma unroll
    for (int n = 0; n < 4; ++n) acc[m][n] = zz;

  stageA(0, 0);
  stageB(0, 0);
  __syncthreads();

  for (int ks = 0; ks < 12; ++ks) {
    const int cu = (ks & 1) << 14;  // 0 / 16384
    if (ks < 11) { stageA(ks + 1, cu ^ 16384); stageB(ks + 1, cu ^ 16384); }
#pragma unroll
    for (int kk = 0; kk < 2; ++kk) {
      bf16x8 a[4], b[4];
#pragma unroll
      for (int m = 0; m < 4; ++m)
        a[m] = *(const bf16x8*)(As + cu + swz(wr * 64 + m * 16 + lo, kk * 32 + hi * 8));
#pragma unroll
      for (int n = 0; n < 4; ++n)
        b[n] = *(const bf16x8*)(Bs + cu + swz(wc * 64 + n * 16 + lo, kk * 32 + hi * 8));
#pragma unroll
      for (int m = 0; m < 4; ++m)
#pragma unroll
        for (int n = 0; n < 4; ++n)
          acc[m][n] = __builtin_amdgcn_mfma_f32_16x16x32_bf16(a[m], b[n], acc[m][n], 0, 0, 0);
    }
    __syncthreads();
  }

#pragma unroll
  for (int m = 0; m < 4; ++m) {
#pragma unroll
    for (int n = 0; n < 4; ++n) {
#pragma unroll
      for (int r = 0; r < 4; ++r) {
        const int R = bm * 128 + wr * 64 + m * 16 + hi * 4 + r;
        const int C = bn * 128 + wc * 64 + n * 16 + lo;
        float v = acc[m][n][r] + bias[MODE == 1 ? R : C];
        if (QS) v *= QL2S_;
        if (MODE == 0) {
          ((short*)out)[((size_t)((R >> 10) * H_ + (C >> 6)) * S_ + (R & 1023)) * HD_ + (C & 63)] = f2bf(v);
        } else if (MODE == 1) {
          ((short*)out)[((size_t)((C >> 10) * H_ + (R >> 6)) * HD_ + (R & 63)) * S_ + (C & 1023)] = f2bf(v);
        } else {
          ((float*)out)[(size_t)R * DIM_ + C] = v;
        }
      }
    }
  }
}

// fused QKV: grid (64, 6, 3)
__global__ __launch_bounds__(256, 2) void k_gemm_qkv(const short* __restrict__ xb,
                                                     const short* __restrict__ WqT,
                                                     const short* __restrict__ WkT,
                                                     const short* __restrict__ WvT,
                                                     const float* __restrict__ bq,
                                                     const float* __restrict__ bk,
                                                     const float* __restrict__ bv,
                                                     short* qo, short* ko, short* vo) {
  __shared__ alignas(16) char smem[65536];
  if (blockIdx.z == 0)
    gemm_body<0, true>(smem, xb, WqT, bq, qo, blockIdx.x, blockIdx.y);
  else if (blockIdx.z == 1)
    gemm_body<0, false>(smem, xb, WkT, bk, ko, blockIdx.x, blockIdx.y);
  else
    gemm_body<1, false>(smem, WvT, xb, bv, vo, blockIdx.y, blockIdx.x);
}

// output projection: grid (6, 64)
__global__ __launch_bounds__(256, 2) void k_gemm_proj(const short* __restrict__ A,
                                                      const short* __restrict__ Bt,
                                                      const float* __restrict__ bias,
                                                      float* out) {
  __shared__ alignas(16) char smem[65536];
  gemm_body<2, false>(smem, A, Bt, bias, out, blockIdx.y, blockIdx.x);
}

// ---------------- flash attention: swapped QK^T + packed P-store + setprio ----------------
// grid: 768 blocks of 256 threads (4 waves x 32 q-rows); 3 blocks/CU, all
// co-resident. Head-local XCD mapping (qt=bid/96, bh=bid%96): all 8 q-tile
// siblings of a head on one XCD -> K/V L2-resident (FETCH ~20MB measured).
// Swapped QK^T (mfma(A=K,B=Q)) -> lane holds S[q=lo][kv=nb*16+hi*4+r]; P
// packs via v_cvt_pk_bf16_f32 -> ds_write_b64; PV reads P as b128 A-frags.
// T5 setprio around both MFMA clusters.
__global__ __launch_bounds__(256, 3) void k_attn(const short* __restrict__ qw,
                                                 const short* __restrict__ kw,
                                                 const short* __restrict__ vtw,
                                                 short* __restrict__ ow) {
  __shared__ alignas(16) char smem[49152];
  char* Kb = smem;            // [2][8192]  K tiles (64 kv x 64 d)
  char* Vb = smem + 16384;    // [2][8192]  Vt tiles (64 d x 64 s)
  char* Ps = smem + 32768;    // [16384]    P (128 q x 64 kv), per-wave quadrants
  const int tid = threadIdx.x;
  const int l = tid & 63, w = tid >> 6;
  const int hi = l >> 4, lo = l & 15;
  const int qt = blockIdx.x / 96;   // head-local XCD: bid%8 == bh%8
  const int bh = blockIdx.x % 96;

  const short* qg = qw  + (size_t)bh * (S_ * HD_) + (qt * 128) * HD_;
  const short* kg = kw  + (size_t)bh * (S_ * HD_);
  const short* vg = vtw + (size_t)bh * (S_ * HD_);

  auto stage = [&](int T, int bufo) {
#pragma unroll
    for (int i = 0; i < 2; ++i) {
      const int gl = i * 256 + tid;
      const int row = gl >> 3;
      const int g = (gl & 7) ^ (row & 7);
      gll16(kg + (T * 64 + row) * 64 + g * 8, Kb + bufo + gl * 16);
    }
#pragma unroll
    for (int i = 0; i < 2; ++i) {
      const int gl = i * 256 + tid;
      const int row = gl >> 3;
      const int g = (gl & 7) ^ (row & 7);
      gll16(vg + row * 1024 + T * 64 + g * 8, Vb + bufo + gl * 16);
    }
  };

  bf16x8 aQ[2][2];
#pragma unroll
  for (int m = 0; m < 2; ++m)
#pragma unroll
    for (int kk = 0; kk < 2; ++kk)
      aQ[m][kk] = *(const bf16x8*)(qg + (w * 32 + m * 16 + lo) * HD_ + kk * 32 + hi * 8);

  f32x4 o_acc[2][4];
  const f32x4 zz = {0.f, 0.f, 0.f, 0.f};
#pragma unroll
  for (int m = 0; m < 2; ++m)
#pragma unroll
    for (int db = 0; db < 4; ++db) o_acc[m][db] = zz;
  float lsum[2] = {0.f, 0.f};

  stage(0, 0);
  __syncthreads();

  for (int t = 0; t < 16; ++t) {
    const int cu = (t & 1) << 13;
    if (t < 15) stage(t + 1, cu ^ 8192);  // issue-early: lands during compute

    // ---- S^T = K Q^T : lane holds S[q=lo][kv=nb*16+hi*4+r]
    f32x4 sacc[2][4];
#pragma unroll
    for (int m = 0; m < 2; ++m)
#pragma unroll
      for (int nb = 0; nb < 4; ++nb) sacc[m][nb] = zz;
    __builtin_amdgcn_s_setprio(1);
#pragma unroll
    for (int kk = 0; kk < 2; ++kk) {
#pragma unroll
      for (int nb = 0; nb < 4; ++nb) {
        const bf16x8 bK = *(const bf16x8*)(Kb + cu + swz(nb * 16 + lo, kk * 32 + hi * 8));
#pragma unroll
        for (int m = 0; m < 2; ++m)
          sacc[m][nb] = __builtin_amdgcn_mfma_f32_16x16x32_bf16(bK, aQ[m][kk], sacc[m][nb], 0, 0, 0);
      }
    }
    __builtin_amdgcn_s_setprio(0);

    // ---- p = 2^(s-1); pack pairs (RNE) and store 4 kv as one b64 ----
#pragma unroll
    for (int m = 0; m < 2; ++m) {
#pragma unroll
      for (int nb = 0; nb < 4; ++nb) {
        const float p0 = exp2a(sacc[m][nb][0] - 1.0f);
        const float p1 = exp2a(sacc[m][nb][1] - 1.0f);
        const float p2 = exp2a(sacc[m][nb][2] - 1.0f);
        const float p3 = exp2a(sacc[m][nb][3] - 1.0f);
        lsum[m] += (p0 + p1) + (p2 + p3);
        uint2 pk;
        pk.x = cvtpk(p0, p1);
        pk.y = cvtpk(p2, p3);
        *(uint2*)(Ps + swz(w * 32 + m * 16 + lo, nb * 16 + hi * 4)) = pk;
      }
    }
    asm volatile("s_waitcnt lgkmcnt(0)" ::: "memory");
    __builtin_amdgcn_sched_barrier(0);

    // ---- O += P V (P A-frags via ds_read_b128, V from LDS) ----
    __builtin_amdgcn_s_setprio(1);
#pragma unroll
    for (int kk = 0; kk < 2; ++kk) {
      bf16x8 aP[2];
#pragma unroll
      for (int m = 0; m < 2; ++m)
        aP[m] = *(const bf16x8*)(Ps + swz(w * 32 + m * 16 + lo, kk * 32 + hi * 8));
#pragma unroll
      for (int db = 0; db < 4; ++db) {
        const bf16x8 bV = *(const bf16x8*)(Vb + cu + swz(db * 16 + lo, kk * 32 + hi * 8));
#pragma unroll
        for (int m = 0; m < 2; ++m)
          o_acc[m][db] = __builtin_amdgcn_mfma_f32_16x16x32_bf16(aP[m], bV, o_acc[m][db], 0, 0, 0);
      }
    }
    __builtin_amdgcn_s_setprio(0);

    __syncthreads();
  }

  // epilogue: complete l over kv (4 hi-groups hold disjoint kv sets), then
  // redistribute to the o_acc row layout (q = hi*4+r lives in lanes 0..15).
  float lF[2];
#pragma unroll
  for (int m = 0; m < 2; ++m) {
    float s = lsum[m];
    s += __shfl_xor(s, 16, 64);
    s += __shfl_xor(s, 32, 64);
    lF[m] = s;  // full row sum for q = lo (all hi groups)
  }
  const int b = bh / H_, h = bh % H_;
#pragma unroll
  for (int m = 0; m < 2; ++m) {
#pragma unroll
    for (int r = 0; r < 4; ++r) {
      const float lr = __shfl(lF[m], hi * 4 + r, 64);
      const float inv = 1.0f / lr;
      const int sg = qt * 128 + w * 32 + m * 16 + hi * 4 + r;
#pragma unroll
      for (int db = 0; db < 4; ++db)
        ow[((size_t)(b * S_ + sg)) * DIM_ + h * HD_ + db * 16 + lo] = f2bf(o_acc[m][db][r] * inv);
    }
  }
}

extern "C" void kernel_launch(void* const* d_in, const int* in_sizes, int n_in,
                              void* d_out, int out_size, void* d_ws, size_t ws_size,
                              hipStream_t stream) {
  const float* x  = (const float*)d_in[0];
  const float* Wq = (const float*)d_in[1];
  const float* bq = (const float*)d_in[2];
  const float* Wk = (const float*)d_in[3];
  const float* bk = (const float*)d_in[4];
  const float* Wv = (const float*)d_in[5];
  const float* bv = (const float*)d_in[6];
  const float* Wp = (const float*)d_in[7];
  const float* bp = (const float*)d_in[8];

  char* ws = (char*)d_ws;
  size_t off = 0;
  auto alloc = [&](size_t bytes) {
    char* p = ws + off;
    off += (bytes + 255) & ~(size_t)255;
    return p;
  };
  short* xb  = (short*)alloc((size_t)8192 * 768 * 2);
  short* WqT = (short*)alloc((size_t)768 * 768 * 2);
  short* WkT = (short*)alloc((size_t)768 * 768 * 2);
  short* WvT = (short*)alloc((size_t)768 * 768 * 2);
  short* WpT = (short*)alloc((size_t)768 * 768 * 2);
  short* qwv = (short*)alloc((size_t)96 * 1024 * 64 * 2);
  short* kwv = (short*)alloc((size_t)96 * 1024 * 64 * 2);
  short* vtw = (short*)alloc((size_t)96 * 1024 * 64 * 2);
  short* owv = (short*)alloc((size_t)8192 * 768 * 2);

  dim3 tb(32, 8), tg(24, 24, 5);
  k_prep<<<tg, tb, 0, stream>>>(x, Wq, Wk, Wv, Wp, xb, WqT, WkT, WvT, WpT);

  k_gemm_qkv<<<dim3(64, 6, 3), 256, 0, stream>>>(xb, WqT, WkT, WvT, bq, bk, bv, qwv, kwv, vtw);

  k_attn<<<B_ * H_ * (S_ / 128), 256, 0, stream>>>(qwv, kwv, vtw, owv);

  k_gemm_proj<<<dim3(6, 64), 256, 0, stream>>>(owv, WpT, bp, (float*)d_out);
}